// Round 1
// baseline (261.462 us; speedup 1.0000x reference)
//
#include <hip/hip_runtime.h>
#include <cstdint>
#include <cstddef>

#define NG 3
#define NB 32
#define NT 1024
#define ND 512
#define NU 512

typedef __bf16 bf16x8 __attribute__((ext_vector_type(8)));
typedef float  f32x4  __attribute__((ext_vector_type(4)));

static __device__ __forceinline__ unsigned int f2bf(float f) {
    union { float f; unsigned int u; } v; v.f = f;
    return (v.u + 0x7FFFu + ((v.u >> 16) & 1u)) >> 16;   // RNE f32->bf16
}

static __device__ __forceinline__ bf16x8 ld_bf16x8(const char* base, int off) {
    return __builtin_bit_cast(bf16x8, *(const uint4*)(base + off));
}

// ---------- kernel 1: qb[g,b,u] = sum_d query[g,b,d]*W1[g,d,u] + b1 + b2 ----------
__global__ __launch_bounds__(256) void prep_qb_kernel(
    const float* __restrict__ query, const float* __restrict__ W1,
    const float* __restrict__ b1, const float* __restrict__ b2,
    float* __restrict__ qb)
{
    __shared__ float qs[NB][ND];                    // 64 KiB
    const int g  = blockIdx.x >> 3;
    const int uc = blockIdx.x & 7;
    const int tid = threadIdx.x;

    const float4* qsrc = (const float4*)(query + (size_t)g * NB * ND);
    #pragma unroll
    for (int i = 0; i < 16; ++i)
        ((float4*)&qs[0][0])[tid + i * 256] = qsrc[tid + i * 256];
    __syncthreads();

    const int u  = uc * 64 + (tid & 63);
    const int b0 = tid >> 6;                        // 0..3
    float acc[8] = {};
    const float* w1col = W1 + (size_t)g * ND * NU + u;
    for (int d = 0; d < ND; ++d) {
        float w = w1col[(size_t)d * NU];            // coalesced over u
        #pragma unroll
        for (int j = 0; j < 8; ++j)
            acc[j] = fmaf(qs[b0 + 4 * j][d], w, acc[j]);  // LDS broadcast
    }
    const float bias = b1[g * NU + u] + b2[g * NU + u];
    #pragma unroll
    for (int j = 0; j < 8; ++j)
        qb[((size_t)g * NB + (b0 + 4 * j)) * NU + u] = acc[j] + bias;
}

// ---------- kernel 2: w2t[g,u,d] = bf16(W2[g,d,u]) ----------
__global__ __launch_bounds__(256) void prep_w2t_kernel(
    const float* __restrict__ W2, unsigned short* __restrict__ w2t)
{
    __shared__ float tile[64][65];                  // +1 pad: conflict-free transpose
    const int g  = blockIdx.x >> 6;
    const int tb = blockIdx.x & 63;
    const int d0 = (tb >> 3) * 64;
    const int u0 = (tb & 7) * 64;
    const int tx = threadIdx.x & 63;
    const int ty = threadIdx.x >> 6;

    const float* src = W2 + (size_t)g * ND * NU;
    #pragma unroll
    for (int k = 0; k < 16; ++k) {
        int r = ty + 4 * k;
        tile[r][tx] = src[(size_t)(d0 + r) * NU + (u0 + tx)];
    }
    __syncthreads();
    unsigned short* dst = w2t + (size_t)g * NU * ND;
    #pragma unroll
    for (int k = 0; k < 16; ++k) {
        int ur = ty + 4 * k;
        dst[(size_t)(u0 + ur) * ND + (d0 + tx)] = (unsigned short)f2bf(tile[tx][ur]);
    }
}

// ---------- kernel 3: fused score = V . tanh(qb + values@W2) + bV ----------
// WG = 256 thr (4 waves), BM=64 t-rows, K=512 fully staged (A), u chunked by 64.
__global__ __launch_bounds__(256) void score_kernel(
    const float* __restrict__ values, const unsigned short* __restrict__ w2t,
    const float* __restrict__ qb, const float* __restrict__ Vvec,
    const float* __restrict__ bV, float* __restrict__ scores)
{
    __shared__ uint4 As4[4096];                     // 64 KiB bf16 A-tile [64t][512d]
    __shared__ uint4 Bs4[4096];                     // 64 KiB bf16 B-chunk [64u][512d]
    __shared__ float qbs[NU];
    __shared__ float Vs[NU];
    char* As = (char*)As4;
    char* Bs = (char*)Bs4;

    const int blk = blockIdx.x;
    const int g   = blk >> 9;                       // 512 = 32 b * 16 t-tiles
    const int rem = blk & 511;
    const int b   = rem >> 4;
    const int t0  = (rem & 15) * 64;
    const int tid = threadIdx.x;

    {   // stage qb(+biases) and V rows
        const float* qsrc = qb + ((size_t)g * NB + b) * NU;
        qbs[tid]       = qsrc[tid];
        qbs[tid + 256] = qsrc[tid + 256];
        Vs[tid]        = Vvec[g * NU + tid];
        Vs[tid + 256]  = Vvec[g * NU + tid + 256];
    }

    // stage A: fp32 -> bf16, XOR-swizzled (row stride 1024B would be 16-way conflict)
    const float* asrc = values + (((size_t)g * NB + b) * NT + t0) * ND;
    #pragma unroll
    for (int pass = 0; pass < 16; ++pass) {
        int idx = pass * 2048 + tid * 8;
        int row = idx >> 9;
        int col = idx & 511;
        float4 v0 = *(const float4*)(asrc + (size_t)row * ND + col);
        float4 v1 = *(const float4*)(asrc + (size_t)row * ND + col + 4);
        uint4 wv;
        wv.x = f2bf(v0.x) | (f2bf(v0.y) << 16);
        wv.y = f2bf(v0.z) | (f2bf(v0.w) << 16);
        wv.z = f2bf(v1.x) | (f2bf(v1.y) << 16);
        wv.w = f2bf(v1.z) | (f2bf(v1.w) << 16);
        int off = (row * 1024 + col * 2) ^ ((row & 7) << 4);
        *(uint4*)(As + off) = wv;
    }

    const int lane    = tid & 63;
    const int wave    = tid >> 6;
    const int lanelow = lane & 15;                  // A: t-row; B: u-col
    const int kgrp    = lane >> 4;                  // k-group (8 bf16 each)
    const int arow    = wave * 16 + lanelow;
    const int abase   = arow * 1024 + kgrp * 16;
    const int aswz    = (arow & 7) << 4;
    const int bswz    = (lanelow & 7) << 4;         // (uu*16+lanelow)&7 == lanelow&7

    float p[4] = {0.f, 0.f, 0.f, 0.f};              // per-lane score partials
    const f32x4 zero = {0.f, 0.f, 0.f, 0.f};

    for (int uc8 = 0; uc8 < 8; ++uc8) {
        __syncthreads();
        // stage B chunk (already bf16, already [u][d])
        const char* bsrc = (const char*)(w2t + ((size_t)g * NU + uc8 * 64) * ND);
        #pragma unroll
        for (int pass = 0; pass < 16; ++pass) {
            int i16 = pass * 256 + tid;             // 16-byte units, 4096 total
            int row = i16 >> 6;                     // 64 units per 1024B row
            int c16 = i16 & 63;
            uint4 v = *(const uint4*)(bsrc + (size_t)row * 1024 + c16 * 16);
            int off = (row * 1024 + c16 * 16) ^ ((row & 7) << 4);
            *(uint4*)(Bs + off) = v;
        }
        __syncthreads();

        f32x4 acc[4];
        #pragma unroll
        for (int uu = 0; uu < 4; ++uu) acc[uu] = zero;

        #pragma unroll
        for (int kk = 0; kk < 16; ++kk) {
            bf16x8 af = ld_bf16x8(As, (abase + kk * 64) ^ aswz);
            #pragma unroll
            for (int uu = 0; uu < 4; ++uu) {
                int boff = ((uu * 16 + lanelow) * 1024 + kk * 64 + kgrp * 16) ^ bswz;
                bf16x8 bfv = ld_bf16x8(Bs, boff);
                acc[uu] = __builtin_amdgcn_mfma_f32_16x16x32_bf16(af, bfv, acc[uu], 0, 0, 0);
            }
        }

        // epilogue: tanh + V-dot, accumulate score partials in registers
        #pragma unroll
        for (int uu = 0; uu < 4; ++uu) {
            int u = uc8 * 64 + uu * 16 + lanelow;
            float qv = qbs[u], vv = Vs[u];
            #pragma unroll
            for (int r = 0; r < 4; ++r) {
                float x  = acc[uu][r] + qv;
                float e  = __expf(-2.f * fabsf(x));
                float th = (1.f - e) / (1.f + e);   // always finite
                th = copysignf(th, x);
                p[r] = fmaf(th, vv, p[r]);
            }
        }
    }

    // reduce over u: sum the 16 lanes of each quarter-wave group
    #pragma unroll
    for (int r = 0; r < 4; ++r) {
        float v = p[r];
        v += __shfl_xor(v, 1);
        v += __shfl_xor(v, 2);
        v += __shfl_xor(v, 4);
        v += __shfl_xor(v, 8);
        p[r] = v;
    }
    if (lanelow == 0) {
        float bv = bV[g];
        #pragma unroll
        for (int r = 0; r < 4; ++r) {
            int t = t0 + wave * 16 + kgrp * 4 + r;  // C/D layout: row=(lane>>4)*4+reg
            scores[((size_t)g * NB + b) * NT + t] = p[r] + bv;
        }
    }
}

// ---------- kernel 4: softmax over T + context = sum_t w_t * values[t,:] ----------
__global__ __launch_bounds__(256) void finish_kernel(
    const float* __restrict__ scores, const float* __restrict__ values,
    float* __restrict__ out_ctx, float* __restrict__ out_w)
{
    __shared__ float sl[NT];
    __shared__ float red[16];
    const int gb  = blockIdx.x;                     // 0..95
    const int tid = threadIdx.x;
    const int lane = tid & 63, wid = tid >> 6;

    const float* srow = scores + (size_t)gb * NT;
    float s[4];
    #pragma unroll
    for (int j = 0; j < 4; ++j) s[j] = srow[tid + 256 * j];

    float m = fmaxf(fmaxf(s[0], s[1]), fmaxf(s[2], s[3]));
    #pragma unroll
    for (int mask = 32; mask; mask >>= 1) m = fmaxf(m, __shfl_xor(m, mask));
    if (lane == 0) red[wid] = m;
    __syncthreads();
    const float gm = fmaxf(fmaxf(red[0], red[1]), fmaxf(red[2], red[3]));

    float e[4], ps = 0.f;
    #pragma unroll
    for (int j = 0; j < 4; ++j) { e[j] = __expf(s[j] - gm); ps += e[j]; }
    #pragma unroll
    for (int mask = 32; mask; mask >>= 1) ps += __shfl_xor(ps, mask);
    if (lane == 0) red[8 + wid] = ps;
    __syncthreads();
    const float inv = 1.f / (red[8] + red[9] + red[10] + red[11]);

    #pragma unroll
    for (int j = 0; j < 4; ++j) {
        float w = e[j] * inv;
        sl[tid + 256 * j] = w;
        out_w[(size_t)gb * NT + tid + 256 * j] = w;
    }
    __syncthreads();

    // context: thread owns 2 consecutive d -> coalesced float2 rows
    const float* vbase = values + (size_t)gb * NT * ND + 2 * tid;
    float2 a0 = {0.f, 0.f}, a1 = {0.f, 0.f}, a2 = {0.f, 0.f}, a3 = {0.f, 0.f};
    #pragma unroll 2
    for (int t = 0; t < NT; t += 4) {
        float2 v0 = *(const float2*)(vbase + (size_t)(t + 0) * ND);
        float2 v1 = *(const float2*)(vbase + (size_t)(t + 1) * ND);
        float2 v2 = *(const float2*)(vbase + (size_t)(t + 2) * ND);
        float2 v3 = *(const float2*)(vbase + (size_t)(t + 3) * ND);
        float w0 = sl[t], w1 = sl[t + 1], w2 = sl[t + 2], w3 = sl[t + 3];
        a0.x = fmaf(w0, v0.x, a0.x); a0.y = fmaf(w0, v0.y, a0.y);
        a1.x = fmaf(w1, v1.x, a1.x); a1.y = fmaf(w1, v1.y, a1.y);
        a2.x = fmaf(w2, v2.x, a2.x); a2.y = fmaf(w2, v2.y, a2.y);
        a3.x = fmaf(w3, v3.x, a3.x); a3.y = fmaf(w3, v3.y, a3.y);
    }
    float2 r;
    r.x = (a0.x + a1.x) + (a2.x + a3.x);
    r.y = (a0.y + a1.y) + (a2.y + a3.y);
    *(float2*)(out_ctx + (size_t)gb * ND + 2 * tid) = r;
}

extern "C" void kernel_launch(void* const* d_in, const int* in_sizes, int n_in,
                              void* d_out, int out_size, void* d_ws, size_t ws_size,
                              hipStream_t stream)
{
    (void)in_sizes; (void)n_in; (void)out_size; (void)ws_size;
    const float* query  = (const float*)d_in[0];
    const float* values = (const float*)d_in[1];
    const float* W1     = (const float*)d_in[2];
    const float* b1     = (const float*)d_in[3];
    const float* W2     = (const float*)d_in[4];
    const float* b2     = (const float*)d_in[5];
    const float* Vv     = (const float*)d_in[6];
    const float* bV     = (const float*)d_in[7];

    float* out_ctx = (float*)d_out;
    float* out_w   = out_ctx + (size_t)NG * NB * ND;

    // workspace: qb (768 KB? no: 192 KiB) | scores (384 KiB) | w2t bf16 (1.5 MiB)
    float* qb     = (float*)d_ws;
    float* scores = qb + (size_t)NG * NB * NU;
    unsigned short* w2t = (unsigned short*)(scores + (size_t)NG * NB * NT);

    prep_qb_kernel <<<NG * 8,              256, 0, stream>>>(query, W1, b1, b2, qb);
    prep_w2t_kernel<<<NG * 64,             256, 0, stream>>>(W2, w2t);
    score_kernel   <<<NG * NB * (NT / 64), 256, 0, stream>>>(values, w2t, qb, Vv, bV, scores);
    finish_kernel  <<<NG * NB,             256, 0, stream>>>(scores, values, out_ctx, out_w);
}

// Round 2
// 181.452 us; speedup vs baseline: 1.4409x; 1.4409x over previous
//
#include <hip/hip_runtime.h>
#include <cstdint>
#include <cstddef>

#define NG 3
#define NB 32
#define NT 1024
#define ND 512
#define NU 512

typedef __bf16 bf16x8 __attribute__((ext_vector_type(8)));
typedef float  f32x16 __attribute__((ext_vector_type(16)));

static __device__ __forceinline__ unsigned int f2bf(float f) {
    union { float f; unsigned int u; } v; v.f = f;
    return (v.u + 0x7FFFu + ((v.u >> 16) & 1u)) >> 16;   // RNE f32->bf16
}

static __device__ __forceinline__ bf16x8 ld_bf16x8(const char* base, int off) {
    return __builtin_bit_cast(bf16x8, *(const uint4*)(base + off));
}

// ---------- kernel 1: qb[g,b,u] = sum_d query[g,b,d]*W1[g,d,u] + b1 + b2 ----------
__global__ __launch_bounds__(256) void prep_qb_kernel(
    const float* __restrict__ query, const float* __restrict__ W1,
    const float* __restrict__ b1, const float* __restrict__ b2,
    float* __restrict__ qb)
{
    __shared__ float qs[NB][ND];                    // 64 KiB
    const int g  = blockIdx.x >> 3;
    const int uc = blockIdx.x & 7;
    const int tid = threadIdx.x;

    const float4* qsrc = (const float4*)(query + (size_t)g * NB * ND);
    #pragma unroll
    for (int i = 0; i < 16; ++i)
        ((float4*)&qs[0][0])[tid + i * 256] = qsrc[tid + i * 256];
    __syncthreads();

    const int u  = uc * 64 + (tid & 63);
    const int b0 = tid >> 6;                        // 0..3
    float acc[8] = {};
    const float* w1col = W1 + (size_t)g * ND * NU + u;
    for (int d = 0; d < ND; ++d) {
        float w = w1col[(size_t)d * NU];            // coalesced over u
        #pragma unroll
        for (int j = 0; j < 8; ++j)
            acc[j] = fmaf(qs[b0 + 4 * j][d], w, acc[j]);  // LDS broadcast
    }
    const float bias = b1[g * NU + u] + b2[g * NU + u];
    #pragma unroll
    for (int j = 0; j < 8; ++j)
        qb[((size_t)g * NB + (b0 + 4 * j)) * NU + u] = acc[j] + bias;
}

// ---------- kernel 2: w2t = swizzled bf16 image of W2^T ----------
// Layout: per g, 16 chunks (u-groups of 32) of 32 KiB. Within a chunk,
// byte(r,d) = (r*1024 + d*2) ^ ((r&7)<<4), r = u&31. This is exactly the
// LDS image score_kernel wants, so staging is a linear global->LDS DMA.
__global__ __launch_bounds__(256) void prep_w2t_kernel(
    const float* __restrict__ W2, char* __restrict__ w2t)
{
    __shared__ float tile[64][65];                  // +1 pad: conflict-free transpose
    const int g  = blockIdx.x >> 6;
    const int tb = blockIdx.x & 63;
    const int d0 = (tb >> 3) * 64;
    const int u0 = (tb & 7) * 64;
    const int tx = threadIdx.x & 63;
    const int ty = threadIdx.x >> 6;

    const float* src = W2 + (size_t)g * ND * NU;
    #pragma unroll
    for (int k = 0; k < 16; ++k) {
        int r = ty + 4 * k;
        tile[r][tx] = src[(size_t)(d0 + r) * NU + (u0 + tx)];   // tile[d_loc][u_loc]
    }
    __syncthreads();
    char* dstg = w2t + (size_t)g * 16 * 32768;
    #pragma unroll
    for (int k = 0; k < 16; ++k) {
        int ul = ty + 4 * k;
        int u  = u0 + ul;
        int d  = d0 + tx;
        unsigned short h = (unsigned short)f2bf(tile[tx][ul]);
        int r = u & 31;
        size_t off = (size_t)(u >> 5) * 32768
                   + (size_t)(((r << 10) | (d << 1)) ^ ((r & 7) << 4));
        *(unsigned short*)(dstg + off) = h;
    }
}

// ---------- kernel 3: fused score = V . tanh(qb + values@W2) + bV ----------
// 256 thr = 4 waves. Wave owns 32 t-rows (BM=128/block). A (values) lives in
// 128 VGPRs as 32 bf16x8 MFMA fragments. B double-buffered in LDS, 32 KiB
// chunks DMA'd with global_load_lds from the pre-swizzled w2t image.
// 2-phase pipeline: {stage next; ds_read+MFMA+epilogue; vmcnt(0); s_barrier}.
__global__ __launch_bounds__(256, 2) void score_kernel(
    const float* __restrict__ values, const char* __restrict__ w2t,
    const float* __restrict__ qb, const float* __restrict__ Vvec,
    const float* __restrict__ bV, float* __restrict__ scores)
{
    __shared__ char  Bs[2][32768];                  // 64 KiB double buffer
    __shared__ float qbs[NU];
    __shared__ float Vs[NU];

    const int blk = blockIdx.x;
    const int g   = blk >> 8;                       // 256 blocks per g
    const int rem = blk & 255;
    const int b   = rem >> 3;
    const int t0  = (rem & 7) << 7;                 // 8 tiles of 128 rows
    const int tid  = threadIdx.x;
    const int lane = tid & 63;
    const int wave = tid >> 6;

    const char* w2g = w2t + ((size_t)g << 19);      // g * 16 * 32768

    // ---- issue stage of chunk 0 ----
    {
        const char* src = w2g + (wave << 13) + (lane << 4);
        char* dst = &Bs[0][wave << 13];
        #pragma unroll
        for (int i = 0; i < 8; ++i)
            __builtin_amdgcn_global_load_lds(
                (const __attribute__((address_space(1))) void*)(src + (i << 10)),
                (__attribute__((address_space(3))) void*)(dst + (i << 10)),
                16, 0, 0);
    }

    // ---- A tile -> registers (bf16 MFMA fragments), 64B-coalesced ----
    bf16x8 afrag[32];
    {
        const int arow_t = t0 + (wave << 5) + (lane & 31);
        const float* arow = values + (((size_t)g * NB + b) * NT + arow_t) * ND;
        const int acol = (lane >> 5) << 3;          // k-half: 0 or 8
        #pragma unroll
        for (int kk = 0; kk < 32; ++kk) {
            const float4* ap = (const float4*)(arow + (kk << 4) + acol);
            float4 v0 = ap[0], v1 = ap[1];
            union { bf16x8 v; unsigned int u[4]; } t;
            t.u[0] = f2bf(v0.x) | (f2bf(v0.y) << 16);
            t.u[1] = f2bf(v0.z) | (f2bf(v0.w) << 16);
            t.u[2] = f2bf(v1.x) | (f2bf(v1.y) << 16);
            t.u[3] = f2bf(v1.z) | (f2bf(v1.w) << 16);
            afrag[kk] = t.v;
        }
    }

    // ---- stage qb(+biases) and V ----
    {
        const float* qsrc = qb + ((size_t)g * NB + b) * NU;
        qbs[tid]       = qsrc[tid];
        qbs[tid + 256] = qsrc[tid + 256];
        Vs[tid]        = Vvec[g * NU + tid];
        Vs[tid + 256]  = Vvec[g * NU + tid + 256];
    }

    asm volatile("s_waitcnt vmcnt(0) lgkmcnt(0)" ::: "memory");
    __builtin_amdgcn_s_barrier();

    const int brow  = lane & 31;
    const int bbase = (brow << 10) + ((lane >> 5) << 4);
    const int bswz  = (lane & 7) << 4;

    float p[16] = {};                               // score partials per C/D reg

    #pragma unroll 1
    for (int uc = 0; uc < 16; ++uc) {
        if (uc < 15) {                              // prefetch next chunk
            const char* src = w2g + (((size_t)(uc + 1)) << 15) + (wave << 13) + (lane << 4);
            char* dst = &Bs[(uc + 1) & 1][wave << 13];
            #pragma unroll
            for (int i = 0; i < 8; ++i)
                __builtin_amdgcn_global_load_lds(
                    (const __attribute__((address_space(1))) void*)(src + (i << 10)),
                    (__attribute__((address_space(3))) void*)(dst + (i << 10)),
                    16, 0, 0);
        }

        const char* bsL = Bs[uc & 1];
        f32x16 acc = (f32x16)(0.0f);
        #pragma unroll
        for (int kk = 0; kk < 32; ++kk) {
            bf16x8 bfv = ld_bf16x8(bsL, (bbase + (kk << 5)) ^ bswz);
            acc = __builtin_amdgcn_mfma_f32_32x32x16_bf16(afrag[kk], bfv, acc, 0, 0, 0);
        }

        // epilogue: tanh + V-dot into per-row partials
        const int u = (uc << 5) + brow;
        const float qv = qbs[u], vv = Vs[u];
        #pragma unroll
        for (int r = 0; r < 16; ++r) {
            float x  = acc[r] + qv;
            float e  = __expf(-2.f * fabsf(x));
            float th = (1.f - e) / (1.f + e);
            th = copysignf(th, x);
            p[r] = fmaf(th, vv, p[r]);
        }

        asm volatile("s_waitcnt vmcnt(0)" ::: "memory");
        __builtin_amdgcn_s_barrier();
    }

    // reduce over u (32 lanes of each half-wave hold distinct u for same rows)
    #pragma unroll
    for (int r = 0; r < 16; ++r) {
        float v = p[r];
        v += __shfl_xor(v, 1);
        v += __shfl_xor(v, 2);
        v += __shfl_xor(v, 4);
        v += __shfl_xor(v, 8);
        v += __shfl_xor(v, 16);
        p[r] = v;
    }
    if ((lane & 31) == 0) {
        const float bv = bV[g];
        float* srow = scores + ((size_t)g * NB + b) * NT + t0 + (wave << 5);
        #pragma unroll
        for (int r = 0; r < 16; ++r) {
            int t_local = (r & 3) + 8 * (r >> 2) + 4 * (lane >> 5);   // C/D 32x32 row map
            srow[t_local] = p[r] + bv;
        }
    }
}

// ---------- kernel 4: softmax over T + context = sum_t w_t * values[t,:] ----------
__global__ __launch_bounds__(256) void finish_kernel(
    const float* __restrict__ scores, const float* __restrict__ values,
    float* __restrict__ out_ctx, float* __restrict__ out_w)
{
    __shared__ float sl[NT];
    __shared__ float red[16];
    const int gb  = blockIdx.x;                     // 0..95
    const int tid = threadIdx.x;
    const int lane = tid & 63, wid = tid >> 6;

    const float* srow = scores + (size_t)gb * NT;
    float s[4];
    #pragma unroll
    for (int j = 0; j < 4; ++j) s[j] = srow[tid + 256 * j];

    float m = fmaxf(fmaxf(s[0], s[1]), fmaxf(s[2], s[3]));
    #pragma unroll
    for (int mask = 32; mask; mask >>= 1) m = fmaxf(m, __shfl_xor(m, mask));
    if (lane == 0) red[wid] = m;
    __syncthreads();
    const float gm = fmaxf(fmaxf(red[0], red[1]), fmaxf(red[2], red[3]));

    float e[4], ps = 0.f;
    #pragma unroll
    for (int j = 0; j < 4; ++j) { e[j] = __expf(s[j] - gm); ps += e[j]; }
    #pragma unroll
    for (int mask = 32; mask; mask >>= 1) ps += __shfl_xor(ps, mask);
    if (lane == 0) red[8 + wid] = ps;
    __syncthreads();
    const float inv = 1.f / (red[8] + red[9] + red[10] + red[11]);

    #pragma unroll
    for (int j = 0; j < 4; ++j) {
        float w = e[j] * inv;
        sl[tid + 256 * j] = w;
        out_w[(size_t)gb * NT + tid + 256 * j] = w;
    }
    __syncthreads();

    const float* vbase = values + (size_t)gb * NT * ND + 2 * tid;
    float2 a0 = {0.f, 0.f}, a1 = {0.f, 0.f}, a2 = {0.f, 0.f}, a3 = {0.f, 0.f};
    #pragma unroll 2
    for (int t = 0; t < NT; t += 4) {
        float2 v0 = *(const float2*)(vbase + (size_t)(t + 0) * ND);
        float2 v1 = *(const float2*)(vbase + (size_t)(t + 1) * ND);
        float2 v2 = *(const float2*)(vbase + (size_t)(t + 2) * ND);
        float2 v3 = *(const float2*)(vbase + (size_t)(t + 3) * ND);
        float w0 = sl[t], w1 = sl[t + 1], w2 = sl[t + 2], w3 = sl[t + 3];
        a0.x = fmaf(w0, v0.x, a0.x); a0.y = fmaf(w0, v0.y, a0.y);
        a1.x = fmaf(w1, v1.x, a1.x); a1.y = fmaf(w1, v1.y, a1.y);
        a2.x = fmaf(w2, v2.x, a2.x); a2.y = fmaf(w2, v2.y, a2.y);
        a3.x = fmaf(w3, v3.x, a3.x); a3.y = fmaf(w3, v3.y, a3.y);
    }
    float2 r;
    r.x = (a0.x + a1.x) + (a2.x + a3.x);
    r.y = (a0.y + a1.y) + (a2.y + a3.y);
    *(float2*)(out_ctx + (size_t)gb * ND + 2 * tid) = r;
}

extern "C" void kernel_launch(void* const* d_in, const int* in_sizes, int n_in,
                              void* d_out, int out_size, void* d_ws, size_t ws_size,
                              hipStream_t stream)
{
    (void)in_sizes; (void)n_in; (void)out_size; (void)ws_size;
    const float* query  = (const float*)d_in[0];
    const float* values = (const float*)d_in[1];
    const float* W1     = (const float*)d_in[2];
    const float* b1     = (const float*)d_in[3];
    const float* W2     = (const float*)d_in[4];
    const float* b2     = (const float*)d_in[5];
    const float* Vv     = (const float*)d_in[6];
    const float* bV     = (const float*)d_in[7];

    float* out_ctx = (float*)d_out;
    float* out_w   = out_ctx + (size_t)NG * NB * ND;

    // ws: qb (192 KiB) | scores (384 KiB) | w2t swizzled bf16 image (1.5 MiB)
    float* qb     = (float*)d_ws;
    float* scores = qb + (size_t)NG * NB * NU;
    char*  w2t    = (char*)(scores + (size_t)NG * NB * NT);

    prep_qb_kernel <<<NG * 8,             256, 0, stream>>>(query, W1, b1, b2, qb);
    prep_w2t_kernel<<<NG * 64,            256, 0, stream>>>(W2, w2t);
    score_kernel   <<<NG * NB * (NT/128), 256, 0, stream>>>(values, w2t, qb, Vv, bV, scores);
    finish_kernel  <<<NG * NB,            256, 0, stream>>>(scores, values, out_ctx, out_w);
}